// Round 1
// baseline (236.051 us; speedup 1.0000x reference)
//
#include <hip/hip_runtime.h>
#include <math.h>

#define HIDDEN   2048
#define NEXPERT  64
#define TOPK     8
#define NTOK     16384
#define TOKB     16          // tokens per block (one 16-row M tile)
#define RSQRT_H  0.02209708691207961
#define WSCALE   64.0f       // keeps f16 Wl split in normal range; undone in epilogue

typedef __attribute__((ext_vector_type(8))) _Float16       v8h;
typedef __attribute__((ext_vector_type(8))) unsigned short v8u;
typedef __attribute__((ext_vector_type(4))) float          v4f;

static __device__ __forceinline__ unsigned short f16b(float x) {
    return __builtin_bit_cast(unsigned short, (_Float16)x);   // v_cvt_f16_f32 (RNE)
}
static __device__ __forceinline__ float f16f(unsigned short u) {
    return (float)__builtin_bit_cast(_Float16, u);
}

// Weight prep into B-fragment order: wf[ks(64)][nt(4)][hl(2)][lane(64)][j(8)] f16.
// B[k][n]: n = nt*16 + (lane&15), k = ks*32 + (lane>>4)*8 + j.  v = w*scale*64.
// Also zeroes out_c (replaces the separate hipMemsetAsync dispatch).
__global__ __launch_bounds__(256) void prep_wf(
    const float* __restrict__ w, const float* __restrict__ scale,
    unsigned short* __restrict__ wf, float* __restrict__ out_c)
{
    int i    = blockIdx.x * 256 + threadIdx.x;   // 131072
    if (i < NEXPERT) out_c[i] = 0.f;
    int j    = i & 7;
    int lane = (i >> 3) & 63;
    int nt   = (i >> 9) & 3;
    int ks   = i >> 11;
    int e    = nt * 16 + (lane & 15);
    int k    = ks * 32 + (lane >> 4) * 8 + j;
    float v  = w[e * HIDDEN + k] * scale[k] * WSCALE;
    unsigned short vh = f16b(v);
    unsigned short vl = f16b(v - f16f(vh));      // Dekker split: v - hi exact in f32
    size_t base = (((size_t)(ks * 4 + nt) * 2) * 64 + lane) * 8 + j;
    wf[base]       = vh;                          // hl=0
    wf[base + 512] = vl;                          // hl=1 (stride 64*8)
}

// 16 tokens/block, 512 thr (8 waves). No X staging in LDS: each wave owns a
// contiguous k-range (8 k-steps = 256 floats/row), loads its A-fragments
// directly from global (per k-step: 16 rows x 128B = 16 full cache lines),
// converts f32 -> split-f16 in registers (same Dekker split as before).
// Main loop is barrier-free; 8 per-wave logit partials combined in LDS.
// logits_raw = Xh*Wh + Xh*Wl + Xl*Wh  (ordering-near-exact, ~1e-9).
__global__ __launch_bounds__(512, 8) void router_main(
    const float* __restrict__ h, const unsigned short* __restrict__ wf,
    const float* __restrict__ pes,
    float* __restrict__ out_w, float* __restrict__ out_i, float* __restrict__ out_c)
{
    __shared__ __align__(16) float lg[8 * 16 * 65];   // [wave][token][expert(+pad)]
    __shared__ float lss[8 * 16];                     // [wave][token] partial sumsq
    __shared__ int   hist[NEXPERT];

    const int tid  = (int)threadIdx.x;
    const int w    = __builtin_amdgcn_readfirstlane(tid >> 6);   // wave 0..7
    const int lane = tid & 63;
    const int m    = lane & 15;                                   // A row / D col idx
    const int quad = lane >> 4;
    const int t0   = (int)blockIdx.x * TOKB;

    if (tid < NEXPERT) hist[tid] = 0;

    // A-fragment source: row (t0+m), k = w*256 + i*32 + quad*8 + j, j=0..7
    const float* xp = h + (size_t)(t0 + m) * HIDDEN + w * 256 + quad * 8;
    // B-fragment source: (ks*4+nt)*1024 + lane*8 ushorts; ks = w*8 + i
    const unsigned short* wq = wf + (size_t)(w * 8) * 4096 + (size_t)lane * 8;

    v4f acc[4];
#pragma unroll
    for (int nt = 0; nt < 4; ++nt) acc[nt] = (v4f)0.f;
    float ssl = 0.f;

    float4 xa = *(const float4*)xp;
    float4 xb = *(const float4*)(xp + 4);

    for (int i = 0; i < 8; ++i) {
        float vv[8] = {xa.x, xa.y, xa.z, xa.w, xb.x, xb.y, xb.z, xb.w};
        if (i < 7) {                        // depth-1 register prefetch
            xa = *(const float4*)(xp + (i + 1) * 32);
            xb = *(const float4*)(xp + (i + 1) * 32 + 4);
        }
        v8u uh, ul;
#pragma unroll
        for (int j = 0; j < 8; ++j) {
            float v = vv[j];
            unsigned short hh = f16b(v);
            uh[j] = hh;
            ul[j] = f16b(v - f16f(hh));     // exact residual in f32, then RNE
            ssl   = fmaf(v, v, ssl);
        }
        v8h ah = __builtin_bit_cast(v8h, uh);
        v8h al = __builtin_bit_cast(v8h, ul);

        const unsigned short* bq = wq + (size_t)i * 4096;
#pragma unroll
        for (int nt = 0; nt < 4; ++nt) {
            const unsigned short* bp = bq + nt * 1024;
            v8h bh = *(const v8h*)bp;
            v8h bl = *(const v8h*)(bp + 512);
            acc[nt] = __builtin_amdgcn_mfma_f32_16x16x32_f16(ah, bh, acc[nt], 0, 0, 0);
            acc[nt] = __builtin_amdgcn_mfma_f32_16x16x32_f16(ah, bl, acc[nt], 0, 0, 0);
            acc[nt] = __builtin_amdgcn_mfma_f32_16x16x32_f16(al, bh, acc[nt], 0, 0, 0);
        }
    }

    // ---- sum of squares: lane covers row m, quad's j-offsets, wave's k-range.
    // Combine the 4 quads -> per-row partial for this wave's 256-float range.
    {
        float s = ssl;
        s += __shfl_xor(s, 16, 64);
        s += __shfl_xor(s, 32, 64);
        if (lane < 16) lss[w * 16 + lane] = s;
    }

    // ---- raw logit partials: D row=(quad*4+reg)=token, col=(lane&15)+nt*16=expert
#pragma unroll
    for (int nt = 0; nt < 4; ++nt)
#pragma unroll
        for (int r = 0; r < 4; ++r)
            lg[(w * 16 + quad * 4 + r) * 65 + nt * 16 + m] = acc[nt][r];

    __syncthreads();

    // ---- top-8 epilogue (R2-verified structure): wave w handles tokens 2w, 2w+1
    for (int i = 0; i < 2; ++i) {
        const int tok = w * 2 + i;
        float lsum = ((lg[(0 * 16 + tok) * 65 + lane] + lg[(1 * 16 + tok) * 65 + lane])
                    + (lg[(2 * 16 + tok) * 65 + lane] + lg[(3 * 16 + tok) * 65 + lane]))
                   + ((lg[(4 * 16 + tok) * 65 + lane] + lg[(5 * 16 + tok) * 65 + lane])
                    + (lg[(6 * 16 + tok) * 65 + lane] + lg[(7 * 16 + tok) * 65 + lane]));
        float s01 = lss[0 * 16 + tok] + lss[1 * 16 + tok];
        float s23 = lss[2 * 16 + tok] + lss[3 * 16 + tok];
        float s45 = lss[4 * 16 + tok] + lss[5 * 16 + tok];
        float s67 = lss[6 * 16 + tok] + lss[7 * 16 + tok];
        double sst = (double)((s01 + s23) + (s45 + s67));
        double rr  = 1.0 / sqrt(sst * (1.0 / (double)HIDDEN) + 1e-6);
        float logit = (float)((double)lsum * rr * (RSQRT_H / (double)WSCALE));

        float work = logit;
        float myval = 0.f; int myidx = 0; float m0 = 0.f;
#pragma unroll
        for (int j = 0; j < TOPK; ++j) {
            float mx = work;
#pragma unroll
            for (int off = 32; off; off >>= 1) mx = fmaxf(mx, __shfl_xor(mx, off, 64));
            unsigned long long msk = __ballot(work == mx);
            int src = __ffsll((long long)msk) - 1;   // ties -> lowest index (jax)
            if (j == 0) m0 = mx;
            if (lane == j) { myval = mx; myidx = src; }
            if (lane == src) work = -3.402823466e38f;
        }

        float ev = (lane < TOPK) ? expf(myval - m0) : 0.f;
        float es = ev;
        es += __shfl_xor(es, 1, 64);
        es += __shfl_xor(es, 2, 64);
        es += __shfl_xor(es, 4, 64);
        if (lane < TOPK) {
            float wgt = (ev / es) * pes[myidx];
            size_t o = (size_t)(t0 + tok) * TOPK + lane;
            out_w[o] = wgt;
            out_i[o] = (float)myidx;                 // d_out read as float32
            atomicAdd(&hist[myidx], 1);
        }
    }

    __syncthreads();
    if (tid < NEXPERT)
        atomicAdd(&out_c[tid], (float)hist[tid]);    // counts are exact small ints
}

extern "C" void kernel_launch(void* const* d_in, const int* in_sizes, int n_in,
                              void* d_out, int out_size, void* d_ws, size_t ws_size,
                              hipStream_t stream) {
    const float* h     = (const float*)d_in[0];   // [4,4096,2048] f32
    const float* scale = (const float*)d_in[1];   // [2048] f32
    const float* w     = (const float*)d_in[2];   // [64,2048] f32
    const float* pes   = (const float*)d_in[3];   // [64] f32

    unsigned short* wf = (unsigned short*)d_ws;   // 512 KB f16 fragment bank

    float* out_w = (float*)d_out;                                  // [16384,8]
    float* out_i = (float*)d_out + (size_t)NTOK * TOPK;            // [16384,8] idx-as-f32
    float* out_c = (float*)d_out + (size_t)NTOK * TOPK * 2;        // [64]

    prep_wf<<<512, 256, 0, stream>>>(w, scale, wf, out_c);

    // 1024 blocks x 512 thr (8 waves); 4 blocks/CU, 32 waves/CU target
    router_main<<<NTOK / TOKB, 512, 0, stream>>>(h, wf, pes, out_w, out_i, out_c);
}

// Round 2
// 231.786 us; speedup vs baseline: 1.0184x; 1.0184x over previous
//
#include <hip/hip_runtime.h>
#include <math.h>

#define HIDDEN   2048
#define NEXPERT  64
#define TOPK     8
#define NTOK     16384
#define TOKB     16          // tokens per block (one 16-row M tile)
#define RSQRT_H  0.02209708691207961
#define WSCALE   64.0f       // keeps f16 Wl split in normal range; undone in epilogue

typedef __attribute__((ext_vector_type(8))) _Float16       v8h;
typedef __attribute__((ext_vector_type(8))) unsigned short v8u;
typedef __attribute__((ext_vector_type(4))) float          v4f;

static __device__ __forceinline__ unsigned short f16b(float x) {
    return __builtin_bit_cast(unsigned short, (_Float16)x);   // v_cvt_f16_f32 (RNE)
}
static __device__ __forceinline__ float f16f(unsigned short u) {
    return (float)__builtin_bit_cast(_Float16, u);
}

// Weight prep into B-fragment order: wf[ks(64)][nt(4)][hl(2)][lane(64)][j(8)] f16.
// B[k][n]: n = nt*16 + (lane&15), k = ks*32 + (lane>>4)*8 + j.  v = w*scale*64.
// Also zeroes out_c (replaces a separate hipMemsetAsync dispatch).
__global__ __launch_bounds__(256) void prep_wf(
    const float* __restrict__ w, const float* __restrict__ scale,
    unsigned short* __restrict__ wf, float* __restrict__ out_c)
{
    int i    = blockIdx.x * 256 + threadIdx.x;   // 131072
    if (i < NEXPERT) out_c[i] = 0.f;
    int j    = i & 7;
    int lane = (i >> 3) & 63;
    int nt   = (i >> 9) & 3;
    int ks   = i >> 11;
    int e    = nt * 16 + (lane & 15);
    int k    = ks * 32 + (lane >> 4) * 8 + j;
    float v  = w[e * HIDDEN + k] * scale[k] * WSCALE;
    unsigned short vh = f16b(v);
    unsigned short vl = f16b(v - f16f(vh));      // Dekker split: v - hi exact in f32
    size_t base = (((size_t)(ks * 4 + nt) * 2) * 64 + lane) * 8 + j;
    wf[base]       = vh;                          // hl=0
    wf[base + 512] = vl;                          // hl=1 (stride 64*8)
}

// 16 tokens/block, 256 thr (4 waves). Wave w owns k-range [w*512, w*512+512) for
// all 16 tokens and self-stages it through a PRIVATE double-buffered LDS region
// via global_load_lds (width 16) -> MLP without VGPR destinations, no barriers
// in the k-loop, counted vmcnt(4) keeps next chunk's 4 loads in flight.
// Global source addresses are pre-swizzled (slot ^ (tok&7)) so the linear LDS
// writes produce a layout whose ds_read_b128 fragment reads are conflict-free.
// logits_raw = Xh*Wh + Xh*Wl + Xl*Wh  (split-f16, ordering-near-exact).
__global__ __launch_bounds__(256, 4) void router_main(
    const float* __restrict__ h, const unsigned short* __restrict__ wf,
    const float* __restrict__ pes,
    float* __restrict__ out_w, float* __restrict__ out_i, float* __restrict__ out_c)
{
    // [stage: 4 waves x 2 bufs x 4KB = 32KB | lss 256B | hist 256B]
    // lg[4][16][65] (16.6KB) aliases stage after the k-loop (barrier-guarded).
    __shared__ __align__(16) char smem[33280];
    float* stage = (float*)smem;
    float* lg    = (float*)smem;
    float* lss   = (float*)(smem + 32768);
    int*   hist  = (int*)(smem + 33024);

    const int tid  = (int)threadIdx.x;
    const int w    = __builtin_amdgcn_readfirstlane(tid >> 6);   // wave 0..3
    const int lane = tid & 63;
    const int m    = lane & 15;                                   // A row / D col idx
    const int quad = lane >> 4;
    const int mx7  = m & 7;
    const int t0   = (int)blockIdx.x * TOKB;

    if (tid < NEXPERT) hist[tid] = 0;

    float* const swb = stage + w * 2048;          // wave's 8KB region (floats)

    v4f acc[4];
#pragma unroll
    for (int nt = 0; nt < 4; ++nt) acc[nt] = (v4f)0.f;
    float ssl = 0.f;

    // ---- prologue: stage chunk 0 (4 x 1KB insts; inst t covers tokens 4t..4t+3)
    // lane i -> LDS base + i*16; global float = X[tok][w*512 + ((i&15)^(tok&7))*4]
#pragma unroll
    for (int t = 0; t < 4; ++t) {
        int tok = t * 4 + quad;
        const float* gp = h + (size_t)(t0 + tok) * HIDDEN + w * 512
                        + ((m ^ (tok & 7)) << 2);
        __builtin_amdgcn_global_load_lds(
            (__attribute__((address_space(1))) const void*)gp,
            (__attribute__((address_space(3))) void*)(swb + t * 256), 16, 0, 0);
    }

#pragma unroll
    for (int c = 0; c < 8; ++c) {
        // previous chunk's ds_reads fully drained before overwriting that buffer
        asm volatile("s_waitcnt lgkmcnt(0)" ::: "memory");
        if (c < 7) {
#pragma unroll
            for (int t = 0; t < 4; ++t) {
                int tok = t * 4 + quad;
                const float* gp = h + (size_t)(t0 + tok) * HIDDEN + w * 512
                                + (c + 1) * 64 + ((m ^ (tok & 7)) << 2);
                __builtin_amdgcn_global_load_lds(
                    (__attribute__((address_space(1))) const void*)gp,
                    (__attribute__((address_space(3))) void*)
                        (swb + ((c + 1) & 1) * 1024 + t * 256), 16, 0, 0);
            }
            asm volatile("s_waitcnt vmcnt(4)" ::: "memory");   // chunk c done; c+1 in flight
        } else {
            asm volatile("s_waitcnt vmcnt(0)" ::: "memory");
        }
        __builtin_amdgcn_sched_barrier(0);

        const float* stg = swb + (c & 1) * 1024 + m * 64;      // this lane's row
#pragma unroll
        for (int s = 0; s < 2; ++s) {
            const int base = s * 8 + quad * 2;                 // 16B slot in row
            const float4 va = *(const float4*)(stg + (((base)     ^ mx7) << 2));
            const float4 vb = *(const float4*)(stg + (((base + 1) ^ mx7) << 2));
            float vv[8] = {va.x, va.y, va.z, va.w, vb.x, vb.y, vb.z, vb.w};
            v8u uh, ul;
#pragma unroll
            for (int j = 0; j < 8; ++j) {
                float v = vv[j];
                unsigned short hh = f16b(v);
                uh[j] = hh;
                ul[j] = f16b(v - f16f(hh));    // exact residual in f32, then RNE
                ssl   = fmaf(v, v, ssl);
            }
            v8h ah = __builtin_bit_cast(v8h, uh);
            v8h al = __builtin_bit_cast(v8h, ul);

            const int ksg = w * 16 + c * 2 + s;                // global k-step
            const unsigned short* bq = wf + (size_t)ksg * 4096 + (size_t)lane * 8;
#pragma unroll
            for (int nt = 0; nt < 4; ++nt) {
                const unsigned short* bp = bq + nt * 1024;
                v8h bh = *(const v8h*)bp;
                v8h bl = *(const v8h*)(bp + 512);
                acc[nt] = __builtin_amdgcn_mfma_f32_16x16x32_f16(ah, bh, acc[nt], 0, 0, 0);
                acc[nt] = __builtin_amdgcn_mfma_f32_16x16x32_f16(ah, bl, acc[nt], 0, 0, 0);
                acc[nt] = __builtin_amdgcn_mfma_f32_16x16x32_f16(al, bh, acc[nt], 0, 0, 0);
            }
        }
    }

    // ---- sum of squares: lane holds row m's partial over this wave's k-range and
    // its quad's j-offsets; combine the 4 quads -> full wave-partial per row.
    {
        float s = ssl;
        s += __shfl_xor(s, 16, 64);
        s += __shfl_xor(s, 32, 64);
        if (lane < 16) lss[w * 16 + lane] = s;
    }
    __syncthreads();   // all staging reads done everywhere -> stage/lg alias safe

    // ---- raw logit partials: D row=(quad*4+reg)=token, col=(lane&15)+nt*16=expert
#pragma unroll
    for (int nt = 0; nt < 4; ++nt)
#pragma unroll
        for (int r = 0; r < 4; ++r)
            lg[(w * 16 + quad * 4 + r) * 65 + nt * 16 + m] = acc[nt][r];
    __syncthreads();

    // ---- top-8 epilogue (R0-verified): wave w handles tokens w*4..w*4+3
    for (int i = 0; i < 4; ++i) {
        const int tok = w * 4 + i;
        float lsum = (lg[tok * 65 + lane]        + lg[1040 + tok * 65 + lane])
                   + (lg[2080 + tok * 65 + lane] + lg[3120 + tok * 65 + lane]);
        float sst4 = (lss[tok] + lss[16 + tok]) + (lss[32 + tok] + lss[48 + tok]);
        double sst = (double)sst4;
        double rr  = 1.0 / sqrt(sst * (1.0 / (double)HIDDEN) + 1e-6);
        float logit = (float)((double)lsum * rr * (RSQRT_H / (double)WSCALE));

        float work = logit;
        float myval = 0.f; int myidx = 0; float m0 = 0.f;
#pragma unroll
        for (int j = 0; j < TOPK; ++j) {
            float mx = work;
#pragma unroll
            for (int off = 32; off; off >>= 1) mx = fmaxf(mx, __shfl_xor(mx, off, 64));
            unsigned long long msk = __ballot(work == mx);
            int src = __ffsll((long long)msk) - 1;   // ties -> lowest index (jax)
            if (j == 0) m0 = mx;
            if (lane == j) { myval = mx; myidx = src; }
            if (lane == src) work = -3.402823466e38f;
        }

        float ev = (lane < TOPK) ? expf(myval - m0) : 0.f;
        float es = ev;
        es += __shfl_xor(es, 1, 64);
        es += __shfl_xor(es, 2, 64);
        es += __shfl_xor(es, 4, 64);
        if (lane < TOPK) {
            float wgt = (ev / es) * pes[myidx];
            size_t o = (size_t)(t0 + tok) * TOPK + lane;
            out_w[o] = wgt;
            out_i[o] = (float)myidx;                 // d_out read as float32
            atomicAdd(&hist[myidx], 1);
        }
    }

    __syncthreads();
    if (tid < NEXPERT)
        atomicAdd(&out_c[tid], (float)hist[tid]);    // counts are exact small ints
}

extern "C" void kernel_launch(void* const* d_in, const int* in_sizes, int n_in,
                              void* d_out, int out_size, void* d_ws, size_t ws_size,
                              hipStream_t stream) {
    const float* h     = (const float*)d_in[0];   // [4,4096,2048] f32
    const float* scale = (const float*)d_in[1];   // [2048] f32
    const float* w     = (const float*)d_in[2];   // [64,2048] f32
    const float* pes   = (const float*)d_in[3];   // [64] f32

    unsigned short* wf = (unsigned short*)d_ws;   // 512 KB f16 fragment bank

    float* out_w = (float*)d_out;                                  // [16384,8]
    float* out_i = (float*)d_out + (size_t)NTOK * TOPK;            // [16384,8] idx-as-f32
    float* out_c = (float*)d_out + (size_t)NTOK * TOPK * 2;        // [64]

    prep_wf<<<512, 256, 0, stream>>>(w, scale, wf, out_c);

    // 1024 blocks x 256 thr (4 waves); 4 blocks/CU, 16 waves/CU
    router_main<<<NTOK / TOKB, 256, 0, stream>>>(h, wf, pes, out_w, out_i, out_c);
}

// Round 3
// 210.256 us; speedup vs baseline: 1.1227x; 1.1024x over previous
//
#include <hip/hip_runtime.h>
#include <math.h>

#define HIDDEN   2048
#define NEXPERT  64
#define TOPK     8
#define NTOK     16384
#define TOKB     32          // tokens per block (two 16-row M tiles)
#define RSQRT_H  0.02209708691207961
#define WSCALE   64.0f       // keeps f16 Wl split in normal range; undone in epilogue

typedef __attribute__((ext_vector_type(8))) _Float16       v8h;
typedef __attribute__((ext_vector_type(8))) unsigned short v8u;
typedef __attribute__((ext_vector_type(4))) float          v4f;

static __device__ __forceinline__ unsigned short f16b(float x) {
    return __builtin_bit_cast(unsigned short, (_Float16)x);   // v_cvt_f16_f32 (RNE)
}
static __device__ __forceinline__ float f16f(unsigned short u) {
    return (float)__builtin_bit_cast(_Float16, u);
}

// Weight prep into B-fragment order: wf[ks(64)][nt(4)][hl(2)][lane(64)][j(8)] f16.
// B[k][n]: n = nt*16 + (lane&15), k = ks*32 + (lane>>4)*8 + j.  v = w*scale*64.
// Also zeroes out_c (replaces a separate hipMemsetAsync dispatch).
__global__ __launch_bounds__(256) void prep_wf(
    const float* __restrict__ w, const float* __restrict__ scale,
    unsigned short* __restrict__ wf, float* __restrict__ out_c)
{
    int i    = blockIdx.x * 256 + threadIdx.x;   // 131072
    if (i < NEXPERT) out_c[i] = 0.f;
    int j    = i & 7;
    int lane = (i >> 3) & 63;
    int nt   = (i >> 9) & 3;
    int ks   = i >> 11;
    int e    = nt * 16 + (lane & 15);
    int k    = ks * 32 + (lane >> 4) * 8 + j;
    float v  = w[e * HIDDEN + k] * scale[k] * WSCALE;
    unsigned short vh = f16b(v);
    unsigned short vl = f16b(v - f16f(vh));      // Dekker split: v - hi exact in f32
    size_t base = (((size_t)(ks * 4 + nt) * 2) * 64 + lane) * 8 + j;
    wf[base]       = vh;                          // hl=0
    wf[base + 512] = vl;                          // hl=1 (stride 64*8)
}

// Convert 8 f32 -> split-f16 hi/lo fragments; accumulate sum of squares.
static __device__ __forceinline__ void cvt8(
    float4 a, float4 b, v8h& ah, v8h& al, float& ss)
{
    float vv[8] = {a.x, a.y, a.z, a.w, b.x, b.y, b.z, b.w};
    v8u uh, ul;
#pragma unroll
    for (int j = 0; j < 8; ++j) {
        float v = vv[j];
        unsigned short hh = f16b(v);
        uh[j] = hh;
        ul[j] = f16b(v - f16f(hh));   // exact residual in f32, then RNE
        ss    = fmaf(v, v, ss);
    }
    ah = __builtin_bit_cast(v8h, uh);
    al = __builtin_bit_cast(v8h, ul);
}

// 32 tokens/block, 512 thr (8 waves). Wave w owns k-range [w*256, w*256+256)
// for ALL 32 tokens (two 16-row M tiles) -> wf traffic halves vs 16-tok blocks
// and each B-fragment group feeds 24 MFMAs. No LDS staging for X: A-fragments
// load straight from global with depth-1 register prefetch. All 8 B-fragments
// of a k-step are loaded into named registers behind a sched_barrier(0) fence,
// forcing the compiler to issue them back-to-back (MLP) and wait late —
// the R0/R2 kernels' serial load->wait->MFMA per nt was the 90us bottleneck.
// logits_raw = Xh*Wh + Xh*Wl + Xl*Wh  (split-f16, ordering-near-exact).
__global__ __launch_bounds__(512, 4) void router_main(
    const float* __restrict__ h, const unsigned short* __restrict__ wf,
    const float* __restrict__ pes,
    float* __restrict__ out_w, float* __restrict__ out_i, float* __restrict__ out_c)
{
    __shared__ __align__(16) float lg[8 * 32 * 66];   // [wave][token][expert+pad] 67584B
    __shared__ float lss[8 * 32];                     // [wave][token] partial sumsq
    __shared__ int   hist[NEXPERT];

    const int tid  = (int)threadIdx.x;
    const int w    = __builtin_amdgcn_readfirstlane(tid >> 6);   // wave 0..7
    const int lane = tid & 63;
    const int m    = lane & 15;                                   // A row idx
    const int quad = lane >> 4;
    const int t0   = (int)blockIdx.x * TOKB;

    if (tid < NEXPERT) hist[tid] = 0;

    // A sources: token rows m (mt0) and 16+m (mt1), k = w*256 + s*32 + quad*8 + j
    const float* xp0 = h + (size_t)(t0 + m) * HIDDEN + w * 256 + quad * 8;
    const float* xp1 = xp0 + (size_t)16 * HIDDEN;
    // B source: ks = w*8 + s; frag base = ks*4096 + nt*1024 (+512 for lo)
    const unsigned short* wq = wf + (size_t)(w * 8) * 4096 + (size_t)lane * 8;

    v4f acc0[4], acc1[4];
#pragma unroll
    for (int nt = 0; nt < 4; ++nt) { acc0[nt] = (v4f)0.f; acc1[nt] = (v4f)0.f; }
    float ss0 = 0.f, ss1 = 0.f;

    float4 xa0 = *(const float4*)xp0, xb0 = *(const float4*)(xp0 + 4);
    float4 xa1 = *(const float4*)xp1, xb1 = *(const float4*)(xp1 + 4);

#pragma unroll
    for (int s = 0; s < 8; ++s) {
        // ---- issue ALL memory for this step first (8 B-frags + next X), then fence
        const unsigned short* bq = wq + (size_t)s * 4096;
        v8h bh[4], bl[4];
#pragma unroll
        for (int nt = 0; nt < 4; ++nt) {
            bh[nt] = *(const v8h*)(bq + nt * 1024);
            bl[nt] = *(const v8h*)(bq + nt * 1024 + 512);
        }
        float4 na0, nb0, na1, nb1;
        if (s < 7) {
            na0 = *(const float4*)(xp0 + (s + 1) * 32);
            nb0 = *(const float4*)(xp0 + (s + 1) * 32 + 4);
            na1 = *(const float4*)(xp1 + (s + 1) * 32);
            nb1 = *(const float4*)(xp1 + (s + 1) * 32 + 4);
        }
        __builtin_amdgcn_sched_barrier(0);   // loads above, consumers below

        // ---- convert current X (overlaps B-load latency)
        v8h ah0, al0, ah1, al1;
        cvt8(xa0, xb0, ah0, al0, ss0);
        cvt8(xa1, xb1, ah1, al1, ss1);

        // ---- 24 MFMAs; per-acc order (ah*bh, ah*bl, al*bh) preserved
#pragma unroll
        for (int nt = 0; nt < 4; ++nt) {
            acc0[nt] = __builtin_amdgcn_mfma_f32_16x16x32_f16(ah0, bh[nt], acc0[nt], 0, 0, 0);
            acc1[nt] = __builtin_amdgcn_mfma_f32_16x16x32_f16(ah1, bh[nt], acc1[nt], 0, 0, 0);
            acc0[nt] = __builtin_amdgcn_mfma_f32_16x16x32_f16(ah0, bl[nt], acc0[nt], 0, 0, 0);
            acc1[nt] = __builtin_amdgcn_mfma_f32_16x16x32_f16(ah1, bl[nt], acc1[nt], 0, 0, 0);
            acc0[nt] = __builtin_amdgcn_mfma_f32_16x16x32_f16(al0, bh[nt], acc0[nt], 0, 0, 0);
            acc1[nt] = __builtin_amdgcn_mfma_f32_16x16x32_f16(al1, bh[nt], acc1[nt], 0, 0, 0);
        }

        if (s < 7) { xa0 = na0; xb0 = nb0; xa1 = na1; xb1 = nb1; }
    }

    // ---- sum of squares: lane holds quad's 64-float share of rows m / 16+m
    {
        float s0 = ss0, s1 = ss1;
        s0 += __shfl_xor(s0, 16, 64); s0 += __shfl_xor(s0, 32, 64);
        s1 += __shfl_xor(s1, 16, 64); s1 += __shfl_xor(s1, 32, 64);
        if (lane < 16) {
            lss[w * 32 + lane]      = s0;
            lss[w * 32 + 16 + lane] = s1;
        }
    }

    // ---- raw logit partials: D row=(quad*4+reg)=token-in-tile, col=nt*16+m
#pragma unroll
    for (int nt = 0; nt < 4; ++nt)
#pragma unroll
        for (int r = 0; r < 4; ++r) {
            lg[(w * 32 + quad * 4 + r) * 66 + nt * 16 + m]      = acc0[nt][r];
            lg[(w * 32 + 16 + quad * 4 + r) * 66 + nt * 16 + m] = acc1[nt][r];
        }
    __syncthreads();

    // ---- top-8 epilogue (R0-verified): wave w handles tokens w*4..w*4+3
    for (int i = 0; i < 4; ++i) {
        const int tok = w * 4 + i;
        float l0 = lg[(0 * 32 + tok) * 66 + lane], l1 = lg[(1 * 32 + tok) * 66 + lane];
        float l2 = lg[(2 * 32 + tok) * 66 + lane], l3 = lg[(3 * 32 + tok) * 66 + lane];
        float l4 = lg[(4 * 32 + tok) * 66 + lane], l5 = lg[(5 * 32 + tok) * 66 + lane];
        float l6 = lg[(6 * 32 + tok) * 66 + lane], l7 = lg[(7 * 32 + tok) * 66 + lane];
        float lsum = ((l0 + l1) + (l2 + l3)) + ((l4 + l5) + (l6 + l7));
        float q01 = lss[0 * 32 + tok] + lss[1 * 32 + tok];
        float q23 = lss[2 * 32 + tok] + lss[3 * 32 + tok];
        float q45 = lss[4 * 32 + tok] + lss[5 * 32 + tok];
        float q67 = lss[6 * 32 + tok] + lss[7 * 32 + tok];
        double sst = (double)((q01 + q23) + (q45 + q67));
        double rr  = 1.0 / sqrt(sst * (1.0 / (double)HIDDEN) + 1e-6);
        float logit = (float)((double)lsum * rr * (RSQRT_H / (double)WSCALE));

        float work = logit;
        float myval = 0.f; int myidx = 0; float m0 = 0.f;
#pragma unroll
        for (int j = 0; j < TOPK; ++j) {
            float mx = work;
#pragma unroll
            for (int off = 32; off; off >>= 1) mx = fmaxf(mx, __shfl_xor(mx, off, 64));
            unsigned long long msk = __ballot(work == mx);
            int src = __ffsll((long long)msk) - 1;   // ties -> lowest index (jax)
            if (j == 0) m0 = mx;
            if (lane == j) { myval = mx; myidx = src; }
            if (lane == src) work = -3.402823466e38f;
        }

        float ev = (lane < TOPK) ? expf(myval - m0) : 0.f;
        float es = ev;
        es += __shfl_xor(es, 1, 64);
        es += __shfl_xor(es, 2, 64);
        es += __shfl_xor(es, 4, 64);
        if (lane < TOPK) {
            float wgt = (ev / es) * pes[myidx];
            size_t o = (size_t)(t0 + tok) * TOPK + lane;
            out_w[o] = wgt;
            out_i[o] = (float)myidx;                 // d_out read as float32
            atomicAdd(&hist[myidx], 1);
        }
    }

    __syncthreads();
    if (tid < NEXPERT)
        atomicAdd(&out_c[tid], (float)hist[tid]);    // counts are exact small ints
}

extern "C" void kernel_launch(void* const* d_in, const int* in_sizes, int n_in,
                              void* d_out, int out_size, void* d_ws, size_t ws_size,
                              hipStream_t stream) {
    const float* h     = (const float*)d_in[0];   // [4,4096,2048] f32
    const float* scale = (const float*)d_in[1];   // [2048] f32
    const float* w     = (const float*)d_in[2];   // [64,2048] f32
    const float* pes   = (const float*)d_in[3];   // [64] f32

    unsigned short* wf = (unsigned short*)d_ws;   // 512 KB f16 fragment bank

    float* out_w = (float*)d_out;                                  // [16384,8]
    float* out_i = (float*)d_out + (size_t)NTOK * TOPK;            // [16384,8] idx-as-f32
    float* out_c = (float*)d_out + (size_t)NTOK * TOPK * 2;        // [64]

    prep_wf<<<512, 256, 0, stream>>>(w, scale, wf, out_c);

    // 512 blocks x 512 thr (8 waves); 2 blocks/CU, 16 waves/CU
    router_main<<<NTOK / TOKB, 512, 0, stream>>>(h, wf, pes, out_w, out_i, out_c);
}